// Round 24
// baseline (212.279 us; speedup 1.0000x reference)
//
#include <hip/hip_runtime.h>
#include <hip/hip_bf16.h>
#include <math.h>

#define NSRC 32768
#define NTOT 65536
#define NDST 32768
#define DH   256
#define SLOTS 64
#define CLBIT 0x80000000u

typedef __attribute__((ext_vector_type(8))) short bf16x8;
typedef __attribute__((ext_vector_type(4))) float f32x4;
typedef __attribute__((ext_vector_type(2))) float f32x2;

__device__ __forceinline__ float wave_reduce(float v) {
#pragma unroll
  for (int off = 32; off > 0; off >>= 1) v += __shfl_xor(v, off, 64);
  return v;
}
// f32 -> bf16 via HW convert (RNE)
__device__ __forceinline__ unsigned short f2bf(float f) {
  __hip_bfloat16 h = __float2bfloat16(f);
  return __builtin_bit_cast(unsigned short, h);
}
// fp8 e4m3 pack/unpack via HW cvt (gfx950 OCP; verified R12+, margin ~12000x)
__device__ __forceinline__ unsigned pk_fp8(float x, float y, float z, float w) {
  int v = __builtin_amdgcn_cvt_pk_fp8_f32(x, y, 0, false);
  v = __builtin_amdgcn_cvt_pk_fp8_f32(z, w, v, true);
  return (unsigned)v;
}
__device__ __forceinline__ float4 unpk_fp8(unsigned u) {
  f32x2 lo = __builtin_amdgcn_cvt_pk_f32_fp8((int)u, false);
  f32x2 hi = __builtin_amdgcn_cvt_pk_f32_fp8((int)u, true);
  return make_float4(lo[0], lo[1], hi[0], hi[1]);
}
__device__ __forceinline__ void add4(float4& a, const float4 v) {
  a.x += v.x; a.y += v.y; a.z += v.z; a.w += v.w;
}
__device__ __forceinline__ float4 sub4(const float4 a, const float4 v) {
  return make_float4(a.x - v.x, a.y - v.y, a.z - v.z, a.w - v.w);
}
__device__ __forceinline__ float dot4(const float4 a, const float4 b) {
  return a.x * b.x + a.y * b.y + a.z * b.z + a.w * b.w;
}
__device__ __forceinline__ float prelu1(float x, float a) {
  return fmaxf(x, 0.f) + a * fminf(x, 0.f);
}
__device__ __forceinline__ float4 hsrc4(const float4 v, const float4 bv,
                                        float alpha, float isc) {
  float4 h;
  h.x = prelu1(v.x + bv.x, alpha) * isc;
  h.y = prelu1(v.y + bv.y, alpha) * isc;
  h.z = prelu1(v.z + bv.z, alpha) * isc;
  h.w = prelu1(v.w + bv.w, alpha) * isc;
  return h;
}
// direct global->LDS DMA, 16B per lane (dest = wave-uniform base + lane*16)
__device__ __forceinline__ void gload_lds16(const void* g, void* l) {
  __builtin_amdgcn_global_load_lds(
      (const __attribute__((address_space(1))) void*)g,
      (__attribute__((address_space(3))) void*)l, 16, 0, 0);
}

// ---------------- prep: cvtW + fixed-slot fill(P) ONLY ----------------------
__global__ __launch_bounds__(256) void k_prep(const float* __restrict__ W,
                                              unsigned short* __restrict__ Wt,
                                              const int* __restrict__ src,
                                              const int* __restrict__ dst,
                                              int* __restrict__ cur,
                                              int* __restrict__ eSrc,
                                              int nE) {
  int bid = blockIdx.x;
  const int t = threadIdx.x;
  if (bid < 256) {  // W transpose+cast
    Wt[bid * 256 + t] = f2bf(W[(size_t)t * 256 + bid]);
    return;
  }
  bid -= 256;
  const int e = bid * 256 + t;
  if (e < nE) {  // pos fill: fixed-slot CSR (64 slots/row; P(deg>64)~1e-20)
    const int d = dst[e] - NSRC;
    const int p = atomicAdd(&cur[d], 1);
    if (p < SLOTS) eSrc[d * SLOTS + p] = src[e];  // claim bit31 starts clear
  }
}

// ---------------- MFMA GEMM (fp8 out) + inn epilogue — 2-phase 64KB LDS -----
// Grid 512 x 512thr; 128 rows/block; feat read once; global_load_lds staging
// (R22: correctness verified). Blocks 0..255 emit inn[row].
__global__ __launch_bounds__(512) void k_gemm(
    const float* __restrict__ A, const unsigned short* __restrict__ Wt,
    const float* __restrict__ b, const float* __restrict__ pa,
    unsigned* __restrict__ mb8, float* __restrict__ inn) {
  __shared__ unsigned short wl[32768];  // 64 KB
  const int bid = blockIdx.x;
  const int t = threadIdx.x;
  const int lane = t & 63;
  const int wv = t >> 6;             // 0..7
  const int ln = lane & 15;
  const int kq = lane >> 4;          // 0..3
  const int row = bid * 128 + wv * 16 + ln;
  const bool is_src = (bid < 256);
  const float alpha = pa[0];

  bf16x8 bs[8];
  const float* ap = A + (size_t)row * 256 + kq * 8;
#pragma unroll
  for (int ks = 0; ks < 8; ++ks) {
    float4 a0 = *(const float4*)(ap + ks * 32);
    float4 a1 = *(const float4*)(ap + ks * 32 + 4);
    bf16x8 v;
    v[0] = (short)f2bf(a0.x); v[1] = (short)f2bf(a0.y);
    v[2] = (short)f2bf(a0.z); v[3] = (short)f2bf(a0.w);
    v[4] = (short)f2bf(a1.x); v[5] = (short)f2bf(a1.y);
    v[6] = (short)f2bf(a1.z); v[7] = (short)f2bf(a1.w);
    bs[ks] = v;
  }

  float ss = 0.f;
  for (int h = 0; h < 2; ++h) {
    __syncthreads();
#pragma unroll
    for (int r = 0; r < 8; ++r) {
      const int flat = r * 512 + t;   // 0..4095; lane component = lane
      const int f = flat >> 6;        // nt*8 + ks, 0..63
      const int ls = flat & 63;
      const int n = h * 128 + (f >> 3) * 16 + (ls & 15);
      const int k = ((ls >> 4) << 3) + (f & 7) * 32;
      gload_lds16(Wt + (size_t)n * 256 + k, wl + flat * 8);
    }
    __syncthreads();

    f32x4 acc[8];
#pragma unroll
    for (int i = 0; i < 8; ++i) acc[i] = (f32x4){0.f, 0.f, 0.f, 0.f};
#pragma unroll
    for (int nt = 0; nt < 8; ++nt) {
#pragma unroll
      for (int ks = 0; ks < 8; ++ks) {
        bf16x8 af = *(const bf16x8*)(wl + ((nt * 8 + ks) * 64 + lane) * 8);
        acc[nt] = __builtin_amdgcn_mfma_f32_16x16x32_bf16(af, bs[ks], acc[nt], 0, 0, 0);
      }
    }
#pragma unroll
    for (int nt = 0; nt < 8; ++nt) {
      mb8[(size_t)row * 64 + h * 32 + nt * 4 + kq] =
          pk_fp8(acc[nt][0], acc[nt][1], acc[nt][2], acc[nt][3]);
      if (is_src) {
        const int n0 = h * 128 + nt * 16 + kq * 4;
        float4 bv = *(const float4*)(b + n0);
        float hx = prelu1(acc[nt][0] + bv.x, alpha);
        float hy = prelu1(acc[nt][1] + bv.y, alpha);
        float hz = prelu1(acc[nt][2] + bv.z, alpha);
        float hw = prelu1(acc[nt][3] + bv.w, alpha);
        ss += hx * hx + hy * hy + hz * hz + hw * hw;
      }
    }
  }
  if (is_src) {
    ss += __shfl_xor(ss, 16, 64);
    ss += __shfl_xor(ss, 32, 64);
    if (kq == 0) inn[row] = 1.0f / fmaxf(sqrtf(ss), 1e-8f);
  }
}

// ---------------- parallel claim: CAS sets bit31 of eSrc IN PLACE -----------
__global__ __launch_bounds__(256) void k_claim(const int* __restrict__ nsrc,
                                               const int* __restrict__ ndst,
                                               const int* __restrict__ cur,
                                               int* __restrict__ eSrc, int nEn) {
  const int i = blockIdx.x * 256 + threadIdx.x;
  if (i >= nEn) return;
  const int d = ndst[i] - NSRC;
  const int s = nsrc[i];
  const int cnt = cur[d];
  const int base = d * SLOTS;
  int j = 0;
  for (; j + 3 < cnt; j += 4) {  // int4 probe: 4 slots per load
    const int4 q = *(const int4*)(eSrc + base + j);
    if (q.x == s && atomicCAS((unsigned*)&eSrc[base + j],     (unsigned)s, s | CLBIT) == (unsigned)s) return;
    if (q.y == s && atomicCAS((unsigned*)&eSrc[base + j + 1], (unsigned)s, s | CLBIT) == (unsigned)s) return;
    if (q.z == s && atomicCAS((unsigned*)&eSrc[base + j + 2], (unsigned)s, s | CLBIT) == (unsigned)s) return;
    if (q.w == s && atomicCAS((unsigned*)&eSrc[base + j + 3], (unsigned)s, s | CLBIT) == (unsigned)s) return;
  }
  for (; j < cnt; ++j) {
    if (eSrc[base + j] == s &&
        atomicCAS((unsigned*)&eSrc[base + j], (unsigned)s, s | CLBIT) == (unsigned)s) return;
  }
}

// ------ fused: agg + prelu + norm + loss + LSE via SPREAD atomics -----------
// R19/R22 single-wave-per-row form (R23 lesson: 2-wave split cost +24us).
// LSE folded in: lane 0 adds exp-terms into slot (row&127) — 128 distinct
// cache lines, per-wave, no extra sync (respects R7 lesson).
__global__ __launch_bounds__(256) void k_fused(const unsigned* __restrict__ mb8,
                                               const float* __restrict__ inn,
                                               const int* __restrict__ cur,
                                               const int* __restrict__ eSrc,
                                               const float* __restrict__ b,
                                               const float* __restrict__ pa,
                                               float* __restrict__ hraw,
                                               float* __restrict__ red2) {
  const int row = blockIdx.x * 4 + (threadIdx.x >> 6);
  const int lane = threadIdx.x & 63;
  const int c = lane * 4;
  const int cnt = cur[row];
  const int base = row * SLOTS;
  const float4 bv = *(const float4*)(b + c);
  const float alpha = pa[0];
  const unsigned* mbl = mb8 + lane;   // lane-fixed base: addr = mbl + s*64

  float4 self = unpk_fp8(mbl[(size_t)(NSRC + row) * 64]);
  float4 aP0 = self, aP1 = {0.f, 0.f, 0.f, 0.f};
  float4 sP0 = {0.f, 0.f, 0.f, 0.f}, sP1 = {0.f, 0.f, 0.f, 0.f};
  float4 aU0 = {0.f, 0.f, 0.f, 0.f}, aU1 = {0.f, 0.f, 0.f, 0.f};
  float4 sU0 = {0.f, 0.f, 0.f, 0.f}, sU1 = {0.f, 0.f, 0.f, 0.f};
  int cN = 0;  // #claimed slots == degN (each neg edge claims exactly one)

  int e = 0;
  for (; e + 3 < cnt; e += 4) {
    const int4 ev = *(const int4*)(eSrc + base + e);  // 4 edges, 1 load
    const int s0 = ev.x & 0x7fffffff, s1 = ev.y & 0x7fffffff;
    const int s2 = ev.z & 0x7fffffff, s3 = ev.w & 0x7fffffff;
    const unsigned r0 = mbl[(size_t)s0 * 64];
    const unsigned r1 = mbl[(size_t)s1 * 64];
    const unsigned r2 = mbl[(size_t)s2 * 64];
    const unsigned r3 = mbl[(size_t)s3 * 64];
    const float i0 = inn[s0], i1 = inn[s1], i2 = inn[s2], i3 = inn[s3];
    float4 v0 = unpk_fp8(r0), v1 = unpk_fp8(r1);
    float4 v2 = unpk_fp8(r2), v3 = unpk_fp8(r3);
    float4 h0 = hsrc4(v0, bv, alpha, i0);
    float4 h1 = hsrc4(v1, bv, alpha, i1);
    float4 h2 = hsrc4(v2, bv, alpha, i2);
    float4 h3 = hsrc4(v3, bv, alpha, i3);
    add4(aP0, v0); add4(aP1, v1); add4(aP0, v2); add4(aP1, v3);
    add4(sP0, h0); add4(sP1, h1); add4(sP0, h2); add4(sP1, h3);
    cN += (ev.x < 0) + (ev.y < 0) + (ev.z < 0) + (ev.w < 0);
    if (ev.x >= 0) { add4(aU0, v0); add4(sU0, h0); }  // unclaimed ~20%
    if (ev.y >= 0) { add4(aU1, v1); add4(sU1, h1); }
    if (ev.z >= 0) { add4(aU0, v2); add4(sU0, h2); }
    if (ev.w >= 0) { add4(aU1, v3); add4(sU1, h3); }
  }
  for (; e < cnt; ++e) {
    const int ev = eSrc[base + e];
    const int s0 = ev & 0x7fffffff;
    const float i0 = inn[s0];
    float4 v0 = unpk_fp8(mbl[(size_t)s0 * 64]);
    float4 h0 = hsrc4(v0, bv, alpha, i0);
    add4(aP0, v0); add4(sP0, h0);
    cN += (ev < 0);
    if (ev >= 0) { add4(aU0, v0); add4(sU0, h0); }
  }
  add4(aP0, aP1); add4(sP0, sP1); add4(aU0, aU1); add4(sU0, sU1);
  float4 aN0 = sub4(aP0, aU0);
  float4 sN0 = sub4(sP0, sU0);

  const float invP = 1.0f / (float)(cnt + 1);
  const float invN = 1.0f / (float)(cN + 1);
  float4 hp, hn;
  hp.x = prelu1(aP0.x * invP + bv.x, alpha);
  hp.y = prelu1(aP0.y * invP + bv.y, alpha);
  hp.z = prelu1(aP0.z * invP + bv.z, alpha);
  hp.w = prelu1(aP0.w * invP + bv.w, alpha);
  hn.x = prelu1(aN0.x * invN + bv.x, alpha);
  hn.y = prelu1(aN0.y * invN + bv.y, alpha);
  hn.z = prelu1(aN0.z * invN + bv.z, alpha);
  hn.w = prelu1(aN0.w * invN + bv.w, alpha);

  *(float4*)(hraw + (size_t)row * 256 + c) = hp;  // h_pos[NSRC:] output

  float ssP = wave_reduce(dot4(hp, hp));
  float ssN = wave_reduce(dot4(hn, hn));
  const float iP = 1.0f / fmaxf(sqrtf(ssP), 1e-8f);
  const float iN = 1.0f / fmaxf(sqrtf(ssN), 1e-8f);
  float4 xp = hp, xn = hn;
  xp.x *= iP; xp.y *= iP; xp.z *= iP; xp.w *= iP;
  xn.x *= iN; xn.y *= iN; xn.z *= iN; xn.w *= iN;

  float pos = wave_reduce(dot4(xp, xn));
  float n1 = wave_reduce(dot4(xp, sN0));
  float n2 = wave_reduce(dot4(xn, sP0));
  if (lane == 0) {
    const float esum = expf(pos) + expf(pos + n1) + expf(pos + n2);
    float* slot = red2 + ((row & 127) << 1);
    atomicAdd(slot, esum);
    atomicAdd(slot + 1, pos);
  }
}

// ---------------- final: 1 block, reduce 128 spread slots -------------------
__global__ __launch_bounds__(128) void k_final(const float* __restrict__ red2,
                                               float* __restrict__ out) {
  const int t = threadIdx.x;  // 128 threads = 2 waves
  float e = red2[2 * t], p = red2[2 * t + 1];
  e = wave_reduce(e);
  p = wave_reduce(p);
  __shared__ float se[2], sp[2];
  if ((t & 63) == 0) { se[t >> 6] = e; sp[t >> 6] = p; }
  __syncthreads();
  if (t == 0) out[0] = logf(se[0] + se[1]) - (sp[0] + sp[1]);
}

extern "C" void kernel_launch(void* const* d_in, const int* in_sizes, int n_in,
                              void* d_out, int out_size, void* d_ws, size_t ws_size,
                              hipStream_t stream) {
  const float* feat = (const float*)d_in[0];
  const int*   src  = (const int*)d_in[1];
  const int*   dst  = (const int*)d_in[2];
  const int*   nsrc = (const int*)d_in[3];
  const int*   ndst = (const int*)d_in[4];
  const float* W    = (const float*)d_in[5];
  const float* b    = (const float*)d_in[6];
  const float* pa   = (const float*)d_in[7];
  const int nE  = in_sizes[1];
  const int nEn = in_sizes[3];
  float* out = (float*)d_out;

  unsigned* mb8 = (unsigned*)d_ws;                       // NTOT*64 uints (fp8)
  unsigned short* Wt = (unsigned short*)(mb8 + (size_t)NTOT * 64);  // 256*256
  float* inn  = (float*)(Wt + 256 * 256);                // NSRC
  int* eSrc = (int*)(inn + NSRC);                        // NDST*SLOTS
  // ---- contiguous zero-region: cur | red2 (one small memset) --------------
  int* cur  = eSrc + (size_t)NDST * SLOTS;               // NDST
  float* red2 = (float*)(cur + NDST);                    // 256
  const size_t zero_bytes = ((size_t)NDST + 256) * 4;

  hipMemsetAsync(cur, 0, zero_bytes, stream);

  const int nbP = (nE + 255) / 256, nbN = (nEn + 255) / 256;
  k_prep<<<256 + nbP, 256, 0, stream>>>(W, Wt, src, dst, cur, eSrc, nE);
  k_gemm<<<512, 512, 0, stream>>>(feat, Wt, b, pa, mb8, inn);
  k_claim<<<nbN, 256, 0, stream>>>(nsrc, ndst, cur, eSrc, nEn);
  k_fused<<<NDST / 4, 256, 0, stream>>>(mb8, inn, cur, eSrc, b, pa,
                                        out + 1, red2);
  k_final<<<1, 128, 0, stream>>>(red2, out);
}

// Round 25
// 168.433 us; speedup vs baseline: 1.2603x; 1.2603x over previous
//
#include <hip/hip_runtime.h>
#include <hip/hip_bf16.h>
#include <math.h>

#define NSRC 32768
#define NTOT 65536
#define NDST 32768
#define DH   256
#define SLOTS 64
#define CLBIT 0x80000000u

typedef __attribute__((ext_vector_type(8))) short bf16x8;
typedef __attribute__((ext_vector_type(4))) float f32x4;
typedef __attribute__((ext_vector_type(2))) float f32x2;

__device__ __forceinline__ float wave_reduce(float v) {
#pragma unroll
  for (int off = 32; off > 0; off >>= 1) v += __shfl_xor(v, off, 64);
  return v;
}
// f32 -> bf16 via HW convert (RNE)
__device__ __forceinline__ unsigned short f2bf(float f) {
  __hip_bfloat16 h = __float2bfloat16(f);
  return __builtin_bit_cast(unsigned short, h);
}
// fp8 e4m3 pack/unpack via HW cvt (gfx950 OCP; verified R12+, margin ~12000x)
__device__ __forceinline__ unsigned pk_fp8(float x, float y, float z, float w) {
  int v = __builtin_amdgcn_cvt_pk_fp8_f32(x, y, 0, false);
  v = __builtin_amdgcn_cvt_pk_fp8_f32(z, w, v, true);
  return (unsigned)v;
}
__device__ __forceinline__ float4 unpk_fp8(unsigned u) {
  f32x2 lo = __builtin_amdgcn_cvt_pk_f32_fp8((int)u, false);
  f32x2 hi = __builtin_amdgcn_cvt_pk_f32_fp8((int)u, true);
  return make_float4(lo[0], lo[1], hi[0], hi[1]);
}
__device__ __forceinline__ void add4(float4& a, const float4 v) {
  a.x += v.x; a.y += v.y; a.z += v.z; a.w += v.w;
}
__device__ __forceinline__ float4 sub4(const float4 a, const float4 v) {
  return make_float4(a.x - v.x, a.y - v.y, a.z - v.z, a.w - v.w);
}
__device__ __forceinline__ float dot4(const float4 a, const float4 b) {
  return a.x * b.x + a.y * b.y + a.z * b.z + a.w * b.w;
}
__device__ __forceinline__ float prelu1(float x, float a) {
  return fmaxf(x, 0.f) + a * fminf(x, 0.f);
}
__device__ __forceinline__ float4 hsrc4(const float4 v, const float4 bv,
                                        float alpha, float isc) {
  float4 h;
  h.x = prelu1(v.x + bv.x, alpha) * isc;
  h.y = prelu1(v.y + bv.y, alpha) * isc;
  h.z = prelu1(v.z + bv.z, alpha) * isc;
  h.w = prelu1(v.w + bv.w, alpha) * isc;
  return h;
}
// direct global->LDS DMA, 16B per lane (dest = wave-uniform base + lane*16)
__device__ __forceinline__ void gload_lds16(const void* g, void* l) {
  __builtin_amdgcn_global_load_lds(
      (const __attribute__((address_space(1))) void*)g,
      (__attribute__((address_space(3))) void*)l, 16, 0, 0);
}

// ---------------- prep: cvtW + fixed-slot fill(P) ONLY ----------------------
__global__ __launch_bounds__(256) void k_prep(const float* __restrict__ W,
                                              unsigned short* __restrict__ Wt,
                                              const int* __restrict__ src,
                                              const int* __restrict__ dst,
                                              int* __restrict__ cur,
                                              int* __restrict__ eSrc,
                                              int nE) {
  int bid = blockIdx.x;
  const int t = threadIdx.x;
  if (bid < 256) {  // W transpose+cast
    Wt[bid * 256 + t] = f2bf(W[(size_t)t * 256 + bid]);
    return;
  }
  bid -= 256;
  const int e = bid * 256 + t;
  if (e < nE) {  // pos fill: fixed-slot CSR (64 slots/row; P(deg>64)~1e-20)
    const int d = dst[e] - NSRC;
    const int p = atomicAdd(&cur[d], 1);
    if (p < SLOTS) eSrc[d * SLOTS + p] = src[e];  // claim bit31 starts clear
  }
}

// ---------------- MFMA GEMM (fp8 out) + inn epilogue — 2-phase 64KB LDS -----
// Grid 512 x 512thr; 128 rows/block; feat read once; global_load_lds staging
// (R22: correctness verified). Blocks 0..255 emit inn[row].
__global__ __launch_bounds__(512) void k_gemm(
    const float* __restrict__ A, const unsigned short* __restrict__ Wt,
    const float* __restrict__ b, const float* __restrict__ pa,
    unsigned* __restrict__ mb8, float* __restrict__ inn) {
  __shared__ unsigned short wl[32768];  // 64 KB
  const int bid = blockIdx.x;
  const int t = threadIdx.x;
  const int lane = t & 63;
  const int wv = t >> 6;             // 0..7
  const int ln = lane & 15;
  const int kq = lane >> 4;          // 0..3
  const int row = bid * 128 + wv * 16 + ln;
  const bool is_src = (bid < 256);
  const float alpha = pa[0];

  bf16x8 bs[8];
  const float* ap = A + (size_t)row * 256 + kq * 8;
#pragma unroll
  for (int ks = 0; ks < 8; ++ks) {
    float4 a0 = *(const float4*)(ap + ks * 32);
    float4 a1 = *(const float4*)(ap + ks * 32 + 4);
    bf16x8 v;
    v[0] = (short)f2bf(a0.x); v[1] = (short)f2bf(a0.y);
    v[2] = (short)f2bf(a0.z); v[3] = (short)f2bf(a0.w);
    v[4] = (short)f2bf(a1.x); v[5] = (short)f2bf(a1.y);
    v[6] = (short)f2bf(a1.z); v[7] = (short)f2bf(a1.w);
    bs[ks] = v;
  }

  float ss = 0.f;
  for (int h = 0; h < 2; ++h) {
    __syncthreads();
#pragma unroll
    for (int r = 0; r < 8; ++r) {
      const int flat = r * 512 + t;   // 0..4095; lane component = lane
      const int f = flat >> 6;        // nt*8 + ks, 0..63
      const int ls = flat & 63;
      const int n = h * 128 + (f >> 3) * 16 + (ls & 15);
      const int k = ((ls >> 4) << 3) + (f & 7) * 32;
      gload_lds16(Wt + (size_t)n * 256 + k, wl + flat * 8);
    }
    __syncthreads();

    f32x4 acc[8];
#pragma unroll
    for (int i = 0; i < 8; ++i) acc[i] = (f32x4){0.f, 0.f, 0.f, 0.f};
#pragma unroll
    for (int nt = 0; nt < 8; ++nt) {
#pragma unroll
      for (int ks = 0; ks < 8; ++ks) {
        bf16x8 af = *(const bf16x8*)(wl + ((nt * 8 + ks) * 64 + lane) * 8);
        acc[nt] = __builtin_amdgcn_mfma_f32_16x16x32_bf16(af, bs[ks], acc[nt], 0, 0, 0);
      }
    }
#pragma unroll
    for (int nt = 0; nt < 8; ++nt) {
      mb8[(size_t)row * 64 + h * 32 + nt * 4 + kq] =
          pk_fp8(acc[nt][0], acc[nt][1], acc[nt][2], acc[nt][3]);
      if (is_src) {
        const int n0 = h * 128 + nt * 16 + kq * 4;
        float4 bv = *(const float4*)(b + n0);
        float hx = prelu1(acc[nt][0] + bv.x, alpha);
        float hy = prelu1(acc[nt][1] + bv.y, alpha);
        float hz = prelu1(acc[nt][2] + bv.z, alpha);
        float hw = prelu1(acc[nt][3] + bv.w, alpha);
        ss += hx * hx + hy * hy + hz * hz + hw * hw;
      }
    }
  }
  if (is_src) {
    ss += __shfl_xor(ss, 16, 64);
    ss += __shfl_xor(ss, 32, 64);
    if (kq == 0) inn[row] = 1.0f / fmaxf(sqrtf(ss), 1e-8f);
  }
}

// ---------------- parallel claim: CAS sets bit31 of eSrc IN PLACE -----------
__global__ __launch_bounds__(256) void k_claim(const int* __restrict__ nsrc,
                                               const int* __restrict__ ndst,
                                               const int* __restrict__ cur,
                                               int* __restrict__ eSrc, int nEn) {
  const int i = blockIdx.x * 256 + threadIdx.x;
  if (i >= nEn) return;
  const int d = ndst[i] - NSRC;
  const int s = nsrc[i];
  const int cnt = cur[d];
  const int base = d * SLOTS;
  int j = 0;
  for (; j + 3 < cnt; j += 4) {  // int4 probe: 4 slots per load
    const int4 q = *(const int4*)(eSrc + base + j);
    if (q.x == s && atomicCAS((unsigned*)&eSrc[base + j],     (unsigned)s, s | CLBIT) == (unsigned)s) return;
    if (q.y == s && atomicCAS((unsigned*)&eSrc[base + j + 1], (unsigned)s, s | CLBIT) == (unsigned)s) return;
    if (q.z == s && atomicCAS((unsigned*)&eSrc[base + j + 2], (unsigned)s, s | CLBIT) == (unsigned)s) return;
    if (q.w == s && atomicCAS((unsigned*)&eSrc[base + j + 3], (unsigned)s, s | CLBIT) == (unsigned)s) return;
  }
  for (; j < cnt; ++j) {
    if (eSrc[base + j] == s &&
        atomicCAS((unsigned*)&eSrc[base + j], (unsigned)s, s | CLBIT) == (unsigned)s) return;
  }
}

// ---------------- fused: agg + prelu + norm + loss (R22 form) ---------------
// lane0 pre-computes esum per row; writes 2 values (esum, pos) -> k_reduce
// scans 2*NDST with no expf. (R24 lesson: NO grid-wide atomics from 32K
// waves through O(100) lines — sims+reduce pair is the right structure.)
__global__ __launch_bounds__(256) void k_fused(const unsigned* __restrict__ mb8,
                                               const float* __restrict__ inn,
                                               const int* __restrict__ cur,
                                               const int* __restrict__ eSrc,
                                               const float* __restrict__ b,
                                               const float* __restrict__ pa,
                                               float* __restrict__ hraw,
                                               float* __restrict__ sims) {
  const int row = blockIdx.x * 4 + (threadIdx.x >> 6);
  const int lane = threadIdx.x & 63;
  const int c = lane * 4;
  const int cnt = cur[row];
  const int base = row * SLOTS;
  const float4 bv = *(const float4*)(b + c);
  const float alpha = pa[0];
  const unsigned* mbl = mb8 + lane;   // lane-fixed base: addr = mbl + s*64

  float4 self = unpk_fp8(mbl[(size_t)(NSRC + row) * 64]);
  float4 aP0 = self, aP1 = {0.f, 0.f, 0.f, 0.f};
  float4 sP0 = {0.f, 0.f, 0.f, 0.f}, sP1 = {0.f, 0.f, 0.f, 0.f};
  float4 aU0 = {0.f, 0.f, 0.f, 0.f}, aU1 = {0.f, 0.f, 0.f, 0.f};
  float4 sU0 = {0.f, 0.f, 0.f, 0.f}, sU1 = {0.f, 0.f, 0.f, 0.f};
  int cN = 0;  // #claimed slots == degN (each neg edge claims exactly one)

  int e = 0;
  for (; e + 3 < cnt; e += 4) {
    const int4 ev = *(const int4*)(eSrc + base + e);  // 4 edges, 1 load
    const int s0 = ev.x & 0x7fffffff, s1 = ev.y & 0x7fffffff;
    const int s2 = ev.z & 0x7fffffff, s3 = ev.w & 0x7fffffff;
    const unsigned r0 = mbl[(size_t)s0 * 64];
    const unsigned r1 = mbl[(size_t)s1 * 64];
    const unsigned r2 = mbl[(size_t)s2 * 64];
    const unsigned r3 = mbl[(size_t)s3 * 64];
    const float i0 = inn[s0], i1 = inn[s1], i2 = inn[s2], i3 = inn[s3];
    float4 v0 = unpk_fp8(r0), v1 = unpk_fp8(r1);
    float4 v2 = unpk_fp8(r2), v3 = unpk_fp8(r3);
    float4 h0 = hsrc4(v0, bv, alpha, i0);
    float4 h1 = hsrc4(v1, bv, alpha, i1);
    float4 h2 = hsrc4(v2, bv, alpha, i2);
    float4 h3 = hsrc4(v3, bv, alpha, i3);
    add4(aP0, v0); add4(aP1, v1); add4(aP0, v2); add4(aP1, v3);
    add4(sP0, h0); add4(sP1, h1); add4(sP0, h2); add4(sP1, h3);
    cN += (ev.x < 0) + (ev.y < 0) + (ev.z < 0) + (ev.w < 0);
    if (ev.x >= 0) { add4(aU0, v0); add4(sU0, h0); }  // unclaimed ~20%
    if (ev.y >= 0) { add4(aU1, v1); add4(sU1, h1); }
    if (ev.z >= 0) { add4(aU0, v2); add4(sU0, h2); }
    if (ev.w >= 0) { add4(aU1, v3); add4(sU1, h3); }
  }
  for (; e < cnt; ++e) {
    const int ev = eSrc[base + e];
    const int s0 = ev & 0x7fffffff;
    const float i0 = inn[s0];
    float4 v0 = unpk_fp8(mbl[(size_t)s0 * 64]);
    float4 h0 = hsrc4(v0, bv, alpha, i0);
    add4(aP0, v0); add4(sP0, h0);
    cN += (ev < 0);
    if (ev >= 0) { add4(aU0, v0); add4(sU0, h0); }
  }
  add4(aP0, aP1); add4(sP0, sP1); add4(aU0, aU1); add4(sU0, sU1);
  float4 aN0 = sub4(aP0, aU0);
  float4 sN0 = sub4(sP0, sU0);

  const float invP = 1.0f / (float)(cnt + 1);
  const float invN = 1.0f / (float)(cN + 1);
  float4 hp, hn;
  hp.x = prelu1(aP0.x * invP + bv.x, alpha);
  hp.y = prelu1(aP0.y * invP + bv.y, alpha);
  hp.z = prelu1(aP0.z * invP + bv.z, alpha);
  hp.w = prelu1(aP0.w * invP + bv.w, alpha);
  hn.x = prelu1(aN0.x * invN + bv.x, alpha);
  hn.y = prelu1(aN0.y * invN + bv.y, alpha);
  hn.z = prelu1(aN0.z * invN + bv.z, alpha);
  hn.w = prelu1(aN0.w * invN + bv.w, alpha);

  *(float4*)(hraw + (size_t)row * 256 + c) = hp;  // h_pos[NSRC:] output

  float ssP = wave_reduce(dot4(hp, hp));
  float ssN = wave_reduce(dot4(hn, hn));
  const float iP = 1.0f / fmaxf(sqrtf(ssP), 1e-8f);
  const float iN = 1.0f / fmaxf(sqrtf(ssN), 1e-8f);
  float4 xp = hp, xn = hn;
  xp.x *= iP; xp.y *= iP; xp.z *= iP; xp.w *= iP;
  xn.x *= iN; xn.y *= iN; xn.z *= iN; xn.w *= iN;

  float pos = wave_reduce(dot4(xp, xn));
  float n1 = wave_reduce(dot4(xp, sN0));
  float n2 = wave_reduce(dot4(xn, sP0));
  if (lane == 0) {
    sims[row] = expf(pos) + expf(pos + n1) + expf(pos + n2);  // esum
    sims[NDST + row] = pos;
  }
}

// ---------------- final log-sum-exp reduce (+ fused finalization) -----------
__global__ __launch_bounds__(256) void k_reduce(const float* __restrict__ sims,
                                                float* __restrict__ red,
                                                int* __restrict__ ticket,
                                                float* __restrict__ out,
                                                int nblocks) {
  const int i = blockIdx.x * 256 + threadIdx.x;  // 2*NDST = 256 blocks
  const float v = sims[i];
  float e = (i < NDST) ? v : 0.f;   // esum half
  float p = (i < NDST) ? 0.f : v;   // pos half
  e = wave_reduce(e);
  p = wave_reduce(p);
  __shared__ float se[4], sp[4];
  const int lane = threadIdx.x & 63, w = threadIdx.x >> 6;
  if (lane == 0) { se[w] = e; sp[w] = p; }
  __syncthreads();
  if (threadIdx.x == 0) {
    atomicAdd(red + 0, se[0] + se[1] + se[2] + se[3]);
    atomicAdd(red + 1, sp[0] + sp[1] + sp[2] + sp[3]);
    __threadfence();
    const int old = atomicAdd(ticket, 1);
    if (old == nblocks - 1) {  // last block: all adds visible
      const float s = atomicAdd(red + 0, 0.0f);
      const float q = atomicAdd(red + 1, 0.0f);
      out[0] = logf(s) - q;
    }
  }
}

extern "C" void kernel_launch(void* const* d_in, const int* in_sizes, int n_in,
                              void* d_out, int out_size, void* d_ws, size_t ws_size,
                              hipStream_t stream) {
  const float* feat = (const float*)d_in[0];
  const int*   src  = (const int*)d_in[1];
  const int*   dst  = (const int*)d_in[2];
  const int*   nsrc = (const int*)d_in[3];
  const int*   ndst = (const int*)d_in[4];
  const float* W    = (const float*)d_in[5];
  const float* b    = (const float*)d_in[6];
  const float* pa   = (const float*)d_in[7];
  const int nE  = in_sizes[1];
  const int nEn = in_sizes[3];
  float* out = (float*)d_out;

  unsigned* mb8 = (unsigned*)d_ws;                       // NTOT*64 uints (fp8)
  unsigned short* Wt = (unsigned short*)(mb8 + (size_t)NTOT * 64);  // 256*256
  float* inn  = (float*)(Wt + 256 * 256);                // NSRC
  float* sims = inn + NSRC;                              // 2*NDST
  int* eSrc = (int*)(sims + 2 * (size_t)NDST);           // NDST*SLOTS
  // ---- contiguous zero-region: cur | red | ticket (one small memset) ------
  int* cur  = eSrc + (size_t)NDST * SLOTS;               // NDST
  float* red = (float*)(cur + NDST);                     // 4
  int* ticket = (int*)(red + 4);                         // 4
  const size_t zero_bytes = ((size_t)NDST + 8) * 4;

  hipMemsetAsync(cur, 0, zero_bytes, stream);

  const int nbP = (nE + 255) / 256, nbN = (nEn + 255) / 256;
  k_prep<<<256 + nbP, 256, 0, stream>>>(W, Wt, src, dst, cur, eSrc, nE);
  k_gemm<<<512, 512, 0, stream>>>(feat, Wt, b, pa, mb8, inn);
  k_claim<<<nbN, 256, 0, stream>>>(nsrc, ndst, cur, eSrc, nEn);
  k_fused<<<NDST / 4, 256, 0, stream>>>(mb8, inn, cur, eSrc, b, pa,
                                        out + 1, sims);
  const int nbR = (2 * NDST) / 256;
  k_reduce<<<nbR, 256, 0, stream>>>(sims, red, ticket, out, nbR);
}